// Round 1
// baseline (57.349 us; speedup 1.0000x reference)
//
#include <hip/hip_runtime.h>

#define NOUT 83
#define NHEART 27
#define NLUNG 28

// Per volume: S=15 slices x 576 feats = 8640 floats = 2160 float4.
// Block handles V=4 contiguous volumes = 8640 float4 contiguous chunk.

__global__ __launch_bounds__(256) void bodyavg_attn_kernel(
    const float* __restrict__ x,
    const float* __restrict__ dzh,   // [27,16] effectively
    const float* __restrict__ dzl,   // [28,16]
    const float* __restrict__ fcw,   // [83,576]
    const float* __restrict__ fcb,   // [83]
    float* __restrict__ out,         // [B,83]
    int B)
{
    __shared__ float  attn_lds[NOUT * 17];   // padded stride 17
    __shared__ float4 xm4s[4][146];          // mean feats per volume, padded row stride

    const int tid = threadIdx.x;
    const int blk = blockIdx.x;

    // ---- Phase 0: channel-attention softmax (83 rows of 16) ----
    if (tid < NOUT) {
        const int o = tid;
        const float* row = (o < NHEART) ? (dzh + o * 16)
                                        : (dzl + ((o - NHEART) % NLUNG) * 16);
        float vals[16];
        #pragma unroll
        for (int c = 0; c < 16; ++c) vals[c] = row[c];
        float m = vals[0];
        #pragma unroll
        for (int c = 1; c < 16; ++c) m = fmaxf(m, vals[c]);
        float s = 0.f;
        #pragma unroll
        for (int c = 0; c < 16; ++c) { vals[c] = expf(vals[c] - m); s += vals[c]; }
        const float inv = 1.0f / s;
        #pragma unroll
        for (int c = 0; c < 16; ++c) attn_lds[o * 17 + c] = vals[c] * inv;
    }

    // ---- Phase 1: mean over 15 slices for 4 volumes (float4, coalesced) ----
    const float4* xq = reinterpret_cast<const float4*>(x) + (size_t)blk * 8640;

    float4 acc0 = make_float4(0.f, 0.f, 0.f, 0.f);
    float4 acc1 = acc0, acc2 = acc0;
    int   off[3], vv[3], qq[3];
    bool  val[3];
    #pragma unroll
    for (int r = 0; r < 3; ++r) {
        const int idx = r * 256 + tid;          // 0..575 (576 = 4 vols x 144 quads)
        const int v = idx / 144;
        const int q = idx - v * 144;
        vv[r] = v; qq[r] = q;
        off[r] = v * 2160 + q;
        val[r] = (idx < 576) && ((blk * 4 + v) < B);
    }
    for (int s = 0; s < 15; ++s) {
        if (val[0]) { float4 t = xq[off[0] + s * 144];
            acc0.x += t.x; acc0.y += t.y; acc0.z += t.z; acc0.w += t.w; }
        if (val[1]) { float4 t = xq[off[1] + s * 144];
            acc1.x += t.x; acc1.y += t.y; acc1.z += t.z; acc1.w += t.w; }
        if (val[2]) { float4 t = xq[off[2] + s * 144];
            acc2.x += t.x; acc2.y += t.y; acc2.z += t.z; acc2.w += t.w; }
    }
    const float sc = 1.0f / 15.0f;
    if (val[0]) xm4s[vv[0]][qq[0]] = make_float4(acc0.x*sc, acc0.y*sc, acc0.z*sc, acc0.w*sc);
    if (val[1]) xm4s[vv[1]][qq[1]] = make_float4(acc1.x*sc, acc1.y*sc, acc1.z*sc, acc1.w*sc);
    if (val[2]) xm4s[vv[2]][qq[2]] = make_float4(acc2.x*sc, acc2.y*sc, acc2.z*sc, acc2.w*sc);

    __syncthreads();

    // ---- Phase 2: out[b,o] = bias[o] + sum_c attn[o,c] * sum_j xm[v][c*36+j]*fcw[o][c*36+j]
    const float4* fcw4 = reinterpret_cast<const float4*>(fcw);
    for (int task = tid; task < 4 * NOUT; task += 256) {
        const int o = task >> 2;
        const int v = task & 3;
        const int b = blk * 4 + v;
        if (b < B) {
            float a2 = fcb[o];
            const float4* wrow = fcw4 + o * 144;
            for (int c = 0; c < 16; ++c) {
                const float a = attn_lds[o * 17 + c];
                float inner = 0.f;
                #pragma unroll
                for (int jj = 0; jj < 9; ++jj) {
                    const float4 w  = wrow[c * 9 + jj];
                    const float4 xv = xm4s[v][c * 9 + jj];
                    inner = fmaf(w.x, xv.x, inner);
                    inner = fmaf(w.y, xv.y, inner);
                    inner = fmaf(w.z, xv.z, inner);
                    inner = fmaf(w.w, xv.w, inner);
                }
                a2 = fmaf(a, inner, a2);
            }
            out[(size_t)b * NOUT + o] = a2;
        }
    }
}

extern "C" void kernel_launch(void* const* d_in, const int* in_sizes, int n_in,
                              void* d_out, int out_size, void* d_ws, size_t ws_size,
                              hipStream_t stream) {
    const float* x   = (const float*)d_in[0];
    const float* dzh = (const float*)d_in[1];
    const float* dzl = (const float*)d_in[2];
    const float* fcw = (const float*)d_in[3];
    const float* fcb = (const float*)d_in[4];
    float* out = (float*)d_out;

    const int B = in_sizes[0] / (15 * 16 * 6 * 6);   // 4096
    const int blocks = (B + 3) / 4;                  // 1024

    hipLaunchKernelGGL(bodyavg_attn_kernel, dim3(blocks), dim3(256), 0, stream,
                       x, dzh, dzl, fcw, fcb, out, B);
}

// Round 2
// 52.653 us; speedup vs baseline: 1.0892x; 1.0892x over previous
//
#include <hip/hip_runtime.h>

#define NOUT 83
#define NHEART 27
#define NLUNG 28

// Per volume: S=15 slices x 576 feats = 8640 floats = 2160 float4.
// Block: 576 threads = 4 volumes x 144 quad-positions, one position/thread.
// Grid: B/4 blocks; 9 waves/block, 3 blocks/CU resident -> 27 waves/CU.

__global__ __launch_bounds__(576, 7) void bodyavg_attn_kernel(
    const float* __restrict__ x,
    const float* __restrict__ dzh,   // [27,16]
    const float* __restrict__ dzl,   // [28,16]
    const float* __restrict__ fcw,   // [83,576]
    const float* __restrict__ fcb,   // [83]
    float* __restrict__ out,         // [B,83]
    int B)
{
    __shared__ float  attn_lds[NOUT * 17];   // padded stride 17
    __shared__ float4 xm4s[4][146];          // mean feats per volume, padded row stride

    const int tid = threadIdx.x;
    const int blk = blockIdx.x;

    // ---- Phase 0: channel-attention softmax (83 rows of 16) ----
    if (tid < NOUT) {
        const int o = tid;
        const float* row = (o < NHEART) ? (dzh + o * 16)
                                        : (dzl + ((o - NHEART) % NLUNG) * 16);
        float vals[16];
        #pragma unroll
        for (int c = 0; c < 16; ++c) vals[c] = row[c];
        float m = vals[0];
        #pragma unroll
        for (int c = 1; c < 16; ++c) m = fmaxf(m, vals[c]);
        float s = 0.f;
        #pragma unroll
        for (int c = 0; c < 16; ++c) { vals[c] = expf(vals[c] - m); s += vals[c]; }
        const float inv = 1.0f / s;
        #pragma unroll
        for (int c = 0; c < 16; ++c) attn_lds[o * 17 + c] = vals[c] * inv;
    }

    // ---- Phase 1: mean over 15 slices, one float4 position per thread ----
    const int v = tid / 144;          // 0..3
    const int q = tid - v * 144;      // 0..143
    const bool vb = (blk * 4 + v) < B;

    if (vb) {
        const float4* p = reinterpret_cast<const float4*>(x)
                          + (size_t)blk * 8640 + v * 2160 + q;
        float ax0 = 0.f, ay0 = 0.f, az0 = 0.f, aw0 = 0.f;   // even slices
        float ax1 = 0.f, ay1 = 0.f, az1 = 0.f, aw1 = 0.f;   // odd slices
        #pragma unroll 5
        for (int s = 0; s < 15; ++s) {
            const float4 t = p[s * 144];
            if (s & 1) { ax1 += t.x; ay1 += t.y; az1 += t.z; aw1 += t.w; }
            else       { ax0 += t.x; ay0 += t.y; az0 += t.z; aw0 += t.w; }
        }
        const float sc = 1.0f / 15.0f;
        xm4s[v][q] = make_float4((ax0 + ax1) * sc, (ay0 + ay1) * sc,
                                 (az0 + az1) * sc, (aw0 + aw1) * sc);
    }

    __syncthreads();

    // ---- Phase 2: out[b,o] = bias[o] + sum_c attn[o,c] * <xm[v], fcw[o]> ----
    if (tid < 4 * NOUT) {
        const int o = tid >> 2;
        const int vv = tid & 3;
        const int b = blk * 4 + vv;
        if (b < B) {
            float a2 = fcb[o];
            const float4* wrow = reinterpret_cast<const float4*>(fcw) + o * 144;
            for (int c = 0; c < 16; ++c) {
                const float a = attn_lds[o * 17 + c];
                float in0 = 0.f, in1 = 0.f;
                #pragma unroll
                for (int jj = 0; jj < 9; ++jj) {
                    const float4 w  = wrow[c * 9 + jj];
                    const float4 xv = xm4s[vv][c * 9 + jj];
                    if (jj & 1) {
                        in1 = fmaf(w.x, xv.x, in1);
                        in1 = fmaf(w.y, xv.y, in1);
                        in1 = fmaf(w.z, xv.z, in1);
                        in1 = fmaf(w.w, xv.w, in1);
                    } else {
                        in0 = fmaf(w.x, xv.x, in0);
                        in0 = fmaf(w.y, xv.y, in0);
                        in0 = fmaf(w.z, xv.z, in0);
                        in0 = fmaf(w.w, xv.w, in0);
                    }
                }
                a2 = fmaf(a, in0 + in1, a2);
            }
            out[(size_t)b * NOUT + o] = a2;
        }
    }
}

extern "C" void kernel_launch(void* const* d_in, const int* in_sizes, int n_in,
                              void* d_out, int out_size, void* d_ws, size_t ws_size,
                              hipStream_t stream) {
    const float* x   = (const float*)d_in[0];
    const float* dzh = (const float*)d_in[1];
    const float* dzl = (const float*)d_in[2];
    const float* fcw = (const float*)d_in[3];
    const float* fcb = (const float*)d_in[4];
    float* out = (float*)d_out;

    const int B = in_sizes[0] / (15 * 16 * 6 * 6);   // 4096
    const int blocks = (B + 3) / 4;                  // 1024

    hipLaunchKernelGGL(bodyavg_attn_kernel, dim3(blocks), dim3(576), 0, stream,
                       x, dzh, dzl, fcw, fcb, out, B);
}

// Round 3
// 50.303 us; speedup vs baseline: 1.1401x; 1.0467x over previous
//
#include <hip/hip_runtime.h>

#define NOUT 83
#define NHEART 27
#define NLUNG 28

// ---------------- K1: slice-mean, pure streaming ----------------
// xm[b*144+q] = (1/15) * sum_s x[b*2160 + s*144 + q]   (float4 quads)
__global__ __launch_bounds__(256) void mean_slices_kernel(
    const float4* __restrict__ x, float4* __restrict__ xm, int total /* B*144 */)
{
    const int g = blockIdx.x * 256 + threadIdx.x;
    if (g >= total) return;
    const int b = g / 144;
    const int q = g - b * 144;
    const float4* p = x + (size_t)b * 2160 + q;

    float4 acc0 = make_float4(0.f, 0.f, 0.f, 0.f);
    float4 acc1 = acc0;
    for (int so = 0; so < 15; so += 5) {
        const float4 t0 = p[(so + 0) * 144];
        const float4 t1 = p[(so + 1) * 144];
        const float4 t2 = p[(so + 2) * 144];
        const float4 t3 = p[(so + 3) * 144];
        const float4 t4 = p[(so + 4) * 144];
        acc0.x += t0.x; acc0.y += t0.y; acc0.z += t0.z; acc0.w += t0.w;
        acc1.x += t1.x; acc1.y += t1.y; acc1.z += t1.z; acc1.w += t1.w;
        acc0.x += t2.x; acc0.y += t2.y; acc0.z += t2.z; acc0.w += t2.w;
        acc1.x += t3.x; acc1.y += t3.y; acc1.z += t3.z; acc1.w += t3.w;
        acc0.x += t4.x; acc0.y += t4.y; acc0.z += t4.z; acc0.w += t4.w;
    }
    const float sc = 1.0f / 15.0f;
    xm[g] = make_float4((acc0.x + acc1.x) * sc, (acc0.y + acc1.y) * sc,
                        (acc0.z + acc1.z) * sc, (acc0.w + acc1.w) * sc);
}

// ---------------- K2: softmax attention + per-disease FC ----------------
// Block: 256 threads = 16 groups of 16 lanes, handles 4 volumes.
// Group owns output row o (strided o += 16); lane l covers quads l+16*jj.
__global__ __launch_bounds__(256) void attn_fc_kernel(
    const float4* __restrict__ xm,   // [B*144] quads
    const float* __restrict__ dzh,   // [27,16]
    const float* __restrict__ dzl,   // [28,16]
    const float4* __restrict__ fcw4, // [83,144] quads
    const float* __restrict__ fcb,   // [83]
    float* __restrict__ out,         // [B,83]
    int B)
{
    __shared__ float  attn_lds[NOUT * 17];
    __shared__ float4 xm4s[576];     // 4 volumes x 144 quads

    const int tid = threadIdx.x;
    const int blk = blockIdx.x;

    // softmax over 16 channels for each of 83 disease rows
    if (tid < NOUT) {
        const int o = tid;
        const float* row = (o < NHEART) ? (dzh + o * 16)
                                        : (dzl + ((o - NHEART) % NLUNG) * 16);
        float vals[16];
        #pragma unroll
        for (int c = 0; c < 16; ++c) vals[c] = row[c];
        float m = vals[0];
        #pragma unroll
        for (int c = 1; c < 16; ++c) m = fmaxf(m, vals[c]);
        float s = 0.f;
        #pragma unroll
        for (int c = 0; c < 16; ++c) { vals[c] = expf(vals[c] - m); s += vals[c]; }
        const float inv = 1.0f / s;
        #pragma unroll
        for (int c = 0; c < 16; ++c) attn_lds[o * 17 + c] = vals[c] * inv;
    }

    // stage 4 volumes of xm
    for (int p = tid; p < 576; p += 256) {
        const int v0 = p / 144;
        if (blk * 4 + v0 < B) xm4s[p] = xm[(size_t)blk * 576 + p];
    }
    __syncthreads();

    const int grp = tid >> 4;
    const int l   = tid & 15;

    int cc[9];
    #pragma unroll
    for (int jj = 0; jj < 9; ++jj) cc[jj] = (l + 16 * jj) / 9;  // channel of quad

    for (int o = grp; o < NOUT; o += 16) {
        float a0 = 0.f, a1 = 0.f, a2 = 0.f, a3 = 0.f;
        const float4* wrow = fcw4 + o * 144;
        #pragma unroll
        for (int jj = 0; jj < 9; ++jj) {
            const int q = l + 16 * jj;
            const float4 w = wrow[q];
            const float  a = attn_lds[o * 17 + cc[jj]];
            const float4 x0 = xm4s[q];
            const float4 x1 = xm4s[144 + q];
            const float4 x2 = xm4s[288 + q];
            const float4 x3 = xm4s[432 + q];
            float i0 = w.x * x0.x; i0 = fmaf(w.y, x0.y, i0); i0 = fmaf(w.z, x0.z, i0); i0 = fmaf(w.w, x0.w, i0);
            float i1 = w.x * x1.x; i1 = fmaf(w.y, x1.y, i1); i1 = fmaf(w.z, x1.z, i1); i1 = fmaf(w.w, x1.w, i1);
            float i2 = w.x * x2.x; i2 = fmaf(w.y, x2.y, i2); i2 = fmaf(w.z, x2.z, i2); i2 = fmaf(w.w, x2.w, i2);
            float i3 = w.x * x3.x; i3 = fmaf(w.y, x3.y, i3); i3 = fmaf(w.z, x3.z, i3); i3 = fmaf(w.w, x3.w, i3);
            a0 = fmaf(a, i0, a0);
            a1 = fmaf(a, i1, a1);
            a2 = fmaf(a, i2, a2);
            a3 = fmaf(a, i3, a3);
        }
        #pragma unroll
        for (int m = 1; m < 16; m <<= 1) {
            a0 += __shfl_xor(a0, m, 16);
            a1 += __shfl_xor(a1, m, 16);
            a2 += __shfl_xor(a2, m, 16);
            a3 += __shfl_xor(a3, m, 16);
        }
        if (l == 0) {
            const float bo = fcb[o];
            const int b0 = blk * 4;
            if (b0 + 0 < B) out[(size_t)(b0 + 0) * NOUT + o] = a0 + bo;
            if (b0 + 1 < B) out[(size_t)(b0 + 1) * NOUT + o] = a1 + bo;
            if (b0 + 2 < B) out[(size_t)(b0 + 2) * NOUT + o] = a2 + bo;
            if (b0 + 3 < B) out[(size_t)(b0 + 3) * NOUT + o] = a3 + bo;
        }
    }
}

// ---------------- Fallback: fused single kernel (R2 version) ----------------
__global__ __launch_bounds__(576, 7) void bodyavg_fused_kernel(
    const float* __restrict__ x,
    const float* __restrict__ dzh,
    const float* __restrict__ dzl,
    const float* __restrict__ fcw,
    const float* __restrict__ fcb,
    float* __restrict__ out,
    int B)
{
    __shared__ float  attn_lds[NOUT * 17];
    __shared__ float4 xm4s[4][146];

    const int tid = threadIdx.x;
    const int blk = blockIdx.x;

    if (tid < NOUT) {
        const int o = tid;
        const float* row = (o < NHEART) ? (dzh + o * 16)
                                        : (dzl + ((o - NHEART) % NLUNG) * 16);
        float vals[16];
        #pragma unroll
        for (int c = 0; c < 16; ++c) vals[c] = row[c];
        float m = vals[0];
        #pragma unroll
        for (int c = 1; c < 16; ++c) m = fmaxf(m, vals[c]);
        float s = 0.f;
        #pragma unroll
        for (int c = 0; c < 16; ++c) { vals[c] = expf(vals[c] - m); s += vals[c]; }
        const float inv = 1.0f / s;
        #pragma unroll
        for (int c = 0; c < 16; ++c) attn_lds[o * 17 + c] = vals[c] * inv;
    }

    const int v = tid / 144;
    const int q = tid - v * 144;
    const bool vb = (blk * 4 + v) < B;

    if (vb) {
        const float4* p = reinterpret_cast<const float4*>(x)
                          + (size_t)blk * 8640 + v * 2160 + q;
        float4 acc0 = make_float4(0.f, 0.f, 0.f, 0.f);
        float4 acc1 = acc0;
        #pragma unroll 5
        for (int s = 0; s < 15; ++s) {
            const float4 t = p[s * 144];
            if (s & 1) { acc1.x += t.x; acc1.y += t.y; acc1.z += t.z; acc1.w += t.w; }
            else       { acc0.x += t.x; acc0.y += t.y; acc0.z += t.z; acc0.w += t.w; }
        }
        const float sc = 1.0f / 15.0f;
        xm4s[v][q] = make_float4((acc0.x + acc1.x) * sc, (acc0.y + acc1.y) * sc,
                                 (acc0.z + acc1.z) * sc, (acc0.w + acc1.w) * sc);
    }

    __syncthreads();

    if (tid < 4 * NOUT) {
        const int o = tid >> 2;
        const int vv = tid & 3;
        const int b = blk * 4 + vv;
        if (b < B) {
            float a2 = fcb[o];
            const float4* wrow = reinterpret_cast<const float4*>(fcw) + o * 144;
            for (int c = 0; c < 16; ++c) {
                const float a = attn_lds[o * 17 + c];
                float in0 = 0.f;
                #pragma unroll
                for (int jj = 0; jj < 9; ++jj) {
                    const float4 w  = wrow[c * 9 + jj];
                    const float4 xv = xm4s[vv][c * 9 + jj];
                    in0 = fmaf(w.x, xv.x, in0);
                    in0 = fmaf(w.y, xv.y, in0);
                    in0 = fmaf(w.z, xv.z, in0);
                    in0 = fmaf(w.w, xv.w, in0);
                }
                a2 = fmaf(a, in0, a2);
            }
            out[(size_t)b * NOUT + o] = a2;
        }
    }
}

extern "C" void kernel_launch(void* const* d_in, const int* in_sizes, int n_in,
                              void* d_out, int out_size, void* d_ws, size_t ws_size,
                              hipStream_t stream) {
    const float* x   = (const float*)d_in[0];
    const float* dzh = (const float*)d_in[1];
    const float* dzl = (const float*)d_in[2];
    const float* fcw = (const float*)d_in[3];
    const float* fcb = (const float*)d_in[4];
    float* out = (float*)d_out;

    const int B = in_sizes[0] / (15 * 16 * 6 * 6);   // 4096
    const size_t ws_needed = (size_t)B * 144 * sizeof(float4);  // 9.4 MB

    if (ws_size >= ws_needed) {
        float4* xm = (float4*)d_ws;
        const int total  = B * 144;
        const int grid1  = (total + 255) / 256;
        const int grid2  = (B + 3) / 4;
        hipLaunchKernelGGL(mean_slices_kernel, dim3(grid1), dim3(256), 0, stream,
                           reinterpret_cast<const float4*>(x), xm, total);
        hipLaunchKernelGGL(attn_fc_kernel, dim3(grid2), dim3(256), 0, stream,
                           xm, dzh, dzl, reinterpret_cast<const float4*>(fcw),
                           fcb, out, B);
    } else {
        const int blocks = (B + 3) / 4;
        hipLaunchKernelGGL(bodyavg_fused_kernel, dim3(blocks), dim3(576), 0, stream,
                           x, dzh, dzl, fcw, fcb, out, B);
    }
}

// Round 4
// 47.291 us; speedup vs baseline: 1.2127x; 1.0637x over previous
//
#include <hip/hip_runtime.h>

#define NOUT 83
#define NHEART 27
#define NLUNG 28

// ---------------- K1: slice-mean, pure streaming, 15 loads in flight ------
// xm[b*144+q] = (1/15) * sum_s x[b*2160 + s*144 + q]   (float4 quads)
__global__ __launch_bounds__(256) void mean_slices_kernel(
    const float4* __restrict__ x, float4* __restrict__ xm, int total /* B*144 */)
{
    const int g = blockIdx.x * 256 + threadIdx.x;
    if (g >= total) return;
    const int b = g / 144;
    const int q = g - b * 144;
    const float4* p = x + (size_t)b * 2160 + q;

    float4 t[15];
    #pragma unroll
    for (int s = 0; s < 15; ++s) t[s] = p[s * 144];   // 15 independent loads

    float sx = 0.f, sy = 0.f, sz = 0.f, sw = 0.f;
    #pragma unroll
    for (int s = 0; s < 15; ++s) {
        sx += t[s].x; sy += t[s].y; sz += t[s].z; sw += t[s].w;
    }
    const float sc = 1.0f / 15.0f;
    xm[g] = make_float4(sx * sc, sy * sc, sz * sc, sw * sc);
}

// ---------------- K2: softmax attention + per-disease FC ------------------
// Block: 256 threads = 16 groups of 16 lanes; block owns 8 volumes.
// Group g handles rows o = g, g+16, ... (6 iters); lane l covers quads
// q = l + 16*jj, jj = 0..8. x kept in registers, shared across the 6 rows.
__global__ __launch_bounds__(256) void attn_fc_kernel(
    const float4* __restrict__ xm,   // [B*144] quads
    const float* __restrict__ dzh,   // [27,16]
    const float* __restrict__ dzl,   // [28,16]
    const float4* __restrict__ fcw4, // [83,144] quads
    const float* __restrict__ fcb,   // [83]
    float* __restrict__ out,         // [B,83]
    int B)
{
    __shared__ float attn_lds[NOUT * 17];

    const int tid = threadIdx.x;
    const int blk = blockIdx.x;

    // softmax over 16 channels for each of 83 disease rows
    if (tid < NOUT) {
        const int o = tid;
        const float* row = (o < NHEART) ? (dzh + o * 16)
                                        : (dzl + ((o - NHEART) % NLUNG) * 16);
        float vals[16];
        #pragma unroll
        for (int c = 0; c < 16; ++c) vals[c] = row[c];
        float m = vals[0];
        #pragma unroll
        for (int c = 1; c < 16; ++c) m = fmaxf(m, vals[c]);
        float s = 0.f;
        #pragma unroll
        for (int c = 0; c < 16; ++c) { vals[c] = expf(vals[c] - m); s += vals[c]; }
        const float inv = 1.0f / s;
        #pragma unroll
        for (int c = 0; c < 16; ++c) attn_lds[o * 17 + c] = vals[c] * inv;
    }
    __syncthreads();

    const int grp = tid >> 4;
    const int l   = tid & 15;
    const int b0  = blk * 8;
    const float4* xmb = xm + (size_t)b0 * 144;

    // 6 output rows per group (row clamped to 0 when past 83; write guarded)
    int oc[6];
    const float4* wr[6];
    #pragma unroll
    for (int oi = 0; oi < 6; ++oi) {
        const int o = grp + 16 * oi;
        oc[oi] = (o < NOUT) ? o : 0;
        wr[oi] = fcw4 + oc[oi] * 144;
    }

    float acc[6][8] = {};

    #pragma unroll 3
    for (int jj = 0; jj < 9; ++jj) {
        const int q  = l + 16 * jj;
        const int cc = q / 9;                 // channel of this quad

        float4 xv[8];
        #pragma unroll
        for (int v = 0; v < 8; ++v) xv[v] = xmb[v * 144 + q];

        #pragma unroll
        for (int oi = 0; oi < 6; ++oi) {
            const float4 w = wr[oi][q];
            const float  a = attn_lds[oc[oi] * 17 + cc];
            const float wx = a * w.x, wy = a * w.y, wz = a * w.z, ww = a * w.w;
            #pragma unroll
            for (int v = 0; v < 8; ++v) {
                acc[oi][v] = fmaf(wx, xv[v].x, acc[oi][v]);
                acc[oi][v] = fmaf(wy, xv[v].y, acc[oi][v]);
                acc[oi][v] = fmaf(wz, xv[v].z, acc[oi][v]);
                acc[oi][v] = fmaf(ww, xv[v].w, acc[oi][v]);
            }
        }
    }

    // transpose-reduce: 8 accumulators over 16 lanes -> lane l holds volume l&7
    #pragma unroll
    for (int oi = 0; oi < 6; ++oi) {
        float r4[4];
        #pragma unroll
        for (int j = 0; j < 4; ++j) {
            const float lo = acc[oi][2 * j], hi = acc[oi][2 * j + 1];
            const bool  up = (l & 1);
            const float keep = up ? hi : lo;
            const float send = up ? lo : hi;
            r4[j] = keep + __shfl_xor(send, 1, 16);
        }
        float r2[2];
        #pragma unroll
        for (int j = 0; j < 2; ++j) {
            const float lo = r4[2 * j], hi = r4[2 * j + 1];
            const bool  up = (l & 2);
            const float keep = up ? hi : lo;
            const float send = up ? lo : hi;
            r2[j] = keep + __shfl_xor(send, 2, 16);
        }
        float r1;
        {
            const float lo = r2[0], hi = r2[1];
            const bool  up = (l & 4);
            const float keep = up ? hi : lo;
            const float send = up ? lo : hi;
            r1 = keep + __shfl_xor(send, 4, 16);
        }
        r1 += __shfl_xor(r1, 8, 16);          // fold lanes 8-15 onto 0-7

        const int o = grp + 16 * oi;
        const int b = b0 + (l & 7);
        if (l < 8 && o < NOUT && b < B)
            out[(size_t)b * NOUT + o] = r1 + fcb[o];
    }
}

// ---------------- Fallback: fused single kernel (R2 version) ----------------
__global__ __launch_bounds__(576, 7) void bodyavg_fused_kernel(
    const float* __restrict__ x,
    const float* __restrict__ dzh,
    const float* __restrict__ dzl,
    const float* __restrict__ fcw,
    const float* __restrict__ fcb,
    float* __restrict__ out,
    int B)
{
    __shared__ float  attn_lds[NOUT * 17];
    __shared__ float4 xm4s[4][146];

    const int tid = threadIdx.x;
    const int blk = blockIdx.x;

    if (tid < NOUT) {
        const int o = tid;
        const float* row = (o < NHEART) ? (dzh + o * 16)
                                        : (dzl + ((o - NHEART) % NLUNG) * 16);
        float vals[16];
        #pragma unroll
        for (int c = 0; c < 16; ++c) vals[c] = row[c];
        float m = vals[0];
        #pragma unroll
        for (int c = 1; c < 16; ++c) m = fmaxf(m, vals[c]);
        float s = 0.f;
        #pragma unroll
        for (int c = 0; c < 16; ++c) { vals[c] = expf(vals[c] - m); s += vals[c]; }
        const float inv = 1.0f / s;
        #pragma unroll
        for (int c = 0; c < 16; ++c) attn_lds[o * 17 + c] = vals[c] * inv;
    }

    const int v = tid / 144;
    const int q = tid - v * 144;
    const bool vb = (blk * 4 + v) < B;

    if (vb) {
        const float4* p = reinterpret_cast<const float4*>(x)
                          + (size_t)blk * 8640 + v * 2160 + q;
        float4 acc0 = make_float4(0.f, 0.f, 0.f, 0.f);
        float4 acc1 = acc0;
        #pragma unroll 5
        for (int s = 0; s < 15; ++s) {
            const float4 t = p[s * 144];
            if (s & 1) { acc1.x += t.x; acc1.y += t.y; acc1.z += t.z; acc1.w += t.w; }
            else       { acc0.x += t.x; acc0.y += t.y; acc0.z += t.z; acc0.w += t.w; }
        }
        const float sc = 1.0f / 15.0f;
        xm4s[v][q] = make_float4((acc0.x + acc1.x) * sc, (acc0.y + acc1.y) * sc,
                                 (acc0.z + acc1.z) * sc, (acc0.w + acc1.w) * sc);
    }

    __syncthreads();

    if (tid < 4 * NOUT) {
        const int o = tid >> 2;
        const int vv = tid & 3;
        const int b = blk * 4 + vv;
        if (b < B) {
            float a2 = fcb[o];
            const float4* wrow = reinterpret_cast<const float4*>(fcw) + o * 144;
            for (int c = 0; c < 16; ++c) {
                const float a = attn_lds[o * 17 + c];
                float in0 = 0.f;
                #pragma unroll
                for (int jj = 0; jj < 9; ++jj) {
                    const float4 w  = wrow[c * 9 + jj];
                    const float4 xv = xm4s[vv][c * 9 + jj];
                    in0 = fmaf(w.x, xv.x, in0);
                    in0 = fmaf(w.y, xv.y, in0);
                    in0 = fmaf(w.z, xv.z, in0);
                    in0 = fmaf(w.w, xv.w, in0);
                }
                a2 = fmaf(a, in0, a2);
            }
            out[(size_t)b * NOUT + o] = a2;
        }
    }
}

extern "C" void kernel_launch(void* const* d_in, const int* in_sizes, int n_in,
                              void* d_out, int out_size, void* d_ws, size_t ws_size,
                              hipStream_t stream) {
    const float* x   = (const float*)d_in[0];
    const float* dzh = (const float*)d_in[1];
    const float* dzl = (const float*)d_in[2];
    const float* fcw = (const float*)d_in[3];
    const float* fcb = (const float*)d_in[4];
    float* out = (float*)d_out;

    const int B = in_sizes[0] / (15 * 16 * 6 * 6);   // 4096
    const size_t ws_needed = (size_t)B * 144 * sizeof(float4);  // 9.4 MB

    if (ws_size >= ws_needed) {
        float4* xm = (float4*)d_ws;
        const int total = B * 144;
        const int grid1 = (total + 255) / 256;
        const int grid2 = (B + 7) / 8;
        hipLaunchKernelGGL(mean_slices_kernel, dim3(grid1), dim3(256), 0, stream,
                           reinterpret_cast<const float4*>(x), xm, total);
        hipLaunchKernelGGL(attn_fc_kernel, dim3(grid2), dim3(256), 0, stream,
                           xm, dzh, dzl, reinterpret_cast<const float4*>(fcw),
                           fcb, out, B);
    } else {
        const int blocks = (B + 3) / 4;
        hipLaunchKernelGGL(bodyavg_fused_kernel, dim3(blocks), dim3(576), 0, stream,
                           x, dzh, dzl, fcw, fcb, out, B);
    }
}

// Round 5
// 38.758 us; speedup vs baseline: 1.4797x; 1.2201x over previous
//
#include <hip/hip_runtime.h>

#define NOUT 83
#define NHEART 27
#define NLUNG 28

// One fused kernel. Block: 384 threads (6 waves), owns 8 volumes.
// Grid: B/8 = 512 blocks -> 2 blocks/CU, FC of one block overlaps
// streaming of the other.
// Phase 1: 8*144=1152 quad positions, 3 rounds of 384; 15 loads in flight.
// Phase 2: 24 groups x 16 lanes; group owns up to 4 o-rows x 8 volumes.
__global__ __launch_bounds__(384, 2) void bodyavg_fused8(
    const float4* __restrict__ x4,   // [B*2160] quads
    const float* __restrict__ dzh,   // [27,16]
    const float* __restrict__ dzl,   // [28,16]
    const float4* __restrict__ fcw4, // [83,144] quads
    const float* __restrict__ fcb,   // [83]
    float* __restrict__ out,         // [B,83]
    int B)
{
    __shared__ float  attn_lds[NOUT * 17];
    __shared__ float4 xms[8 * 144];          // mean feats, 8 volumes

    const int tid = threadIdx.x;
    const int blk = blockIdx.x;
    const int b0  = blk * 8;

    // ---- Phase 0: channel softmax for 83 disease rows ----
    if (tid < NOUT) {
        const int o = tid;
        const float* row = (o < NHEART) ? (dzh + o * 16)
                                        : (dzl + ((o - NHEART) % NLUNG) * 16);
        float vals[16];
        #pragma unroll
        for (int c = 0; c < 16; ++c) vals[c] = row[c];
        float m = vals[0];
        #pragma unroll
        for (int c = 1; c < 16; ++c) m = fmaxf(m, vals[c]);
        float s = 0.f;
        #pragma unroll
        for (int c = 0; c < 16; ++c) { vals[c] = expf(vals[c] - m); s += vals[c]; }
        const float inv = 1.0f / s;
        #pragma unroll
        for (int c = 0; c < 16; ++c) attn_lds[o * 17 + c] = vals[c] * inv;
    }

    // ---- Phase 1: slice-mean, 3 rounds of one position per thread ----
    const float4* xb = x4 + (size_t)b0 * 2160;
    #pragma unroll
    for (int r = 0; r < 3; ++r) {
        const int p = tid + r * 384;         // 0..1151
        const int v = p / 144;
        const int q = p - v * 144;
        if (b0 + v < B) {
            const float4* src = xb + v * 2160 + q;
            float4 t[15];
            #pragma unroll
            for (int s = 0; s < 15; ++s) t[s] = src[s * 144];
            float sx = 0.f, sy = 0.f, sz = 0.f, sw = 0.f;
            #pragma unroll
            for (int s = 0; s < 15; ++s) {
                sx += t[s].x; sy += t[s].y; sz += t[s].z; sw += t[s].w;
            }
            const float sc = 1.0f / 15.0f;
            xms[p] = make_float4(sx * sc, sy * sc, sz * sc, sw * sc);
        } else {
            xms[p] = make_float4(0.f, 0.f, 0.f, 0.f);
        }
    }
    __syncthreads();

    // ---- Phase 2: FC. 24 groups; group g -> rows o = g + 24k, k=0..3 ----
    const int grp = tid >> 4;     // 0..23
    const int l   = tid & 15;

    int oc[4];
    const float4* wr[4];
    #pragma unroll
    for (int k = 0; k < 4; ++k) {
        const int o = grp + 24 * k;
        oc[k] = (o < NOUT) ? o : 0;
        wr[k] = fcw4 + oc[k] * 144;
    }

    float acc[4][8] = {};

    #pragma unroll 3
    for (int jj = 0; jj < 9; ++jj) {
        const int q  = l + 16 * jj;
        const int cc = q / 9;                // channel of this quad

        float4 xv[8];
        #pragma unroll
        for (int v = 0; v < 8; ++v) xv[v] = xms[v * 144 + q];

        #pragma unroll
        for (int k = 0; k < 4; ++k) {
            const float4 w = wr[k][q];
            const float  a = attn_lds[oc[k] * 17 + cc];
            const float wx = a * w.x, wy = a * w.y, wz = a * w.z, ww = a * w.w;
            #pragma unroll
            for (int v = 0; v < 8; ++v) {
                acc[k][v] = fmaf(wx, xv[v].x, acc[k][v]);
                acc[k][v] = fmaf(wy, xv[v].y, acc[k][v]);
                acc[k][v] = fmaf(wz, xv[v].z, acc[k][v]);
                acc[k][v] = fmaf(ww, xv[v].w, acc[k][v]);
            }
        }
    }

    // transpose-reduce within 16 lanes: lane l<8 ends with volume l's sum
    #pragma unroll
    for (int k = 0; k < 4; ++k) {
        float r4[4];
        #pragma unroll
        for (int j = 0; j < 4; ++j) {
            const float lo = acc[k][2 * j], hi = acc[k][2 * j + 1];
            const bool  up = (l & 1);
            const float keep = up ? hi : lo;
            const float send = up ? lo : hi;
            r4[j] = keep + __shfl_xor(send, 1, 16);
        }
        float r2[2];
        #pragma unroll
        for (int j = 0; j < 2; ++j) {
            const float lo = r4[2 * j], hi = r4[2 * j + 1];
            const bool  up = (l & 2);
            const float keep = up ? hi : lo;
            const float send = up ? lo : hi;
            r2[j] = keep + __shfl_xor(send, 2, 16);
        }
        float r1;
        {
            const float lo = r2[0], hi = r2[1];
            const bool  up = (l & 4);
            const float keep = up ? hi : lo;
            const float send = up ? lo : hi;
            r1 = keep + __shfl_xor(send, 4, 16);
        }
        r1 += __shfl_xor(r1, 8, 16);         // fold lanes 8-15 onto 0-7

        const int o = grp + 24 * k;
        const int b = b0 + (l & 7);
        if (l < 8 && o < NOUT && b < B)
            out[(size_t)b * NOUT + o] = r1 + fcb[o];
    }
}

extern "C" void kernel_launch(void* const* d_in, const int* in_sizes, int n_in,
                              void* d_out, int out_size, void* d_ws, size_t ws_size,
                              hipStream_t stream) {
    const float* x   = (const float*)d_in[0];
    const float* dzh = (const float*)d_in[1];
    const float* dzl = (const float*)d_in[2];
    const float* fcw = (const float*)d_in[3];
    const float* fcb = (const float*)d_in[4];
    float* out = (float*)d_out;

    const int B = in_sizes[0] / (15 * 16 * 6 * 6);   // 4096
    const int blocks = (B + 7) / 8;                  // 512

    hipLaunchKernelGGL(bodyavg_fused8, dim3(blocks), dim3(384), 0, stream,
                       reinterpret_cast<const float4*>(x), dzh, dzl,
                       reinterpret_cast<const float4*>(fcw), fcb, out, B);
}